// Round 1
// baseline (7327.657 us; speedup 1.0000x reference)
//
#include <hip/hip_runtime.h>
#include <stdint.h>

typedef unsigned int u32;
typedef unsigned short u16;
typedef __attribute__((ext_vector_type(8))) __bf16 bf16x8;
typedef __attribute__((ext_vector_type(4))) float f32x4;

#define NSTEPS 256
// ---- workspace layout ----
#define XB_BYTES   67108864u              // x as bf16: 512*256*256*2
#define SL_OFF     XB_BYTES               // h slices: [slot][group][wg] 2KB each
#define SLICE_BYTES 2048u
#define GRP_BYTES   65536u                // 32 wg * 2KB
#define SLOT_BYTES  524288u               // 8 groups
#define CNT_OFF    (SL_OFF + 2u * SLOT_BYTES)
// ---- LDS layout ----
#define W_ROWB 1536                       // 768 bf16 per weight row
#define H_OFF  98304                      // 64 rows * 1536
#define LDS_TOTAL 163840                  // + 64 rows * 1024 (h tile) = 160 KiB exactly

static __device__ __forceinline__ u16 f2bf(float f) {
  u32 u = __builtin_bit_cast(u32, f);
  return (u16)((u + 0x7fffu + ((u >> 16) & 1u)) >> 16);   // RNE
}
static __device__ __forceinline__ float bf2f(u16 h) {
  u32 u = ((u32)h) << 16;
  return __builtin_bit_cast(float, u);
}
static __device__ __forceinline__ float sigm(float x) {
  return __builtin_amdgcn_rcpf(1.f + __builtin_amdgcn_exp2f(-1.4426950408889634f * x));
}
static __device__ __forceinline__ float tanh_(float x) {
  return 1.f - 2.f * __builtin_amdgcn_rcpf(1.f + __builtin_amdgcn_exp2f(2.8853900817779268f * x));
}

__global__ void cvt_x(const float* __restrict__ x, u16* __restrict__ xb) {
  int i = blockIdx.x * 256 + threadIdx.x;          // one float4 per thread
  float4 v = ((const float4*)x)[i];
  ushort4 o;
  o.x = f2bf(v.x); o.y = f2bf(v.y); o.z = f2bf(v.z); o.w = f2bf(v.w);
  ((ushort4*)xb)[i] = o;
}

// 256 WGs (1/CU): group = wg&7 owns batch rows [grp*64, +64); wgN = wg>>3 owns
// gate cols {g*512 + wgN*16 + j : g in 0..3, j in 0..15}. Weights LDS-resident.
__global__ void __launch_bounds__(256) lstm_main(
    const u16* __restrict__ xb,
    const float* __restrict__ W_ih, const float* __restrict__ W_hh,
    const float* __restrict__ b_ih, const float* __restrict__ b_hh,
    const float* __restrict__ W_out, const float* __restrict__ b_out,
    float* __restrict__ out, char* __restrict__ ws)
{
  __shared__ char smem[LDS_TOTAL];
  const int tid = threadIdx.x;
  const int wg  = blockIdx.x;
  const int grp = wg & 7;
  const int wgN = wg >> 3;
  const int lane = tid & 63;
  const int wv   = tid >> 6;
  const int rh = wv >> 1;        // wave's row-half of the 64x64 output
  const int ch = wv & 1;         // wave's col-half
  const int cc = lane & 15;
  const int hi = lane >> 4;
  const int q  = cc & 3;         // j-offset within 4-col subtile
  const int gs = cc >> 2;        // gate index of this lane's column

  // ---- one-time: weight slice -> LDS, bf16, XOR-swizzled 16B granules ----
  // LDS row r (0..63): p = r>>2 (j_local), g = r&3 -> n = g*512 + wgN*16 + p
  for (int i = tid; i < 64 * 192; i += 256) {
    int r = i / 192;
    int k = (i - r * 192) * 4;
    int n = (r & 3) * 512 + wgN * 16 + (r >> 2);
    float4 v = (k < 256) ? *(const float4*)(W_ih + n * 256 + k)
                         : *(const float4*)(W_hh + n * 512 + (k - 256));
    u32 lo  = (u32)f2bf(v.x) | ((u32)f2bf(v.y) << 16);
    u32 hi2 = (u32)f2bf(v.z) | ((u32)f2bf(v.w) << 16);
    int addr = r * W_ROWB + ((k * 2) ^ ((r & 7) << 4));
    *(uint2*)(smem + addr) = make_uint2(lo, hi2);
  }

  float biasv[2];
  #pragma unroll
  for (int nt = 0; nt < 2; ++nt) {
    int n = gs * 512 + wgN * 16 + (ch * 2 + nt) * 4 + q;
    biasv[nt] = b_ih[n] + b_hh[n];
  }

  u32* cnt = (u32*)(ws + CNT_OFF + grp * 128);
  char* slices    = ws + SL_OFF;
  const char* grpslices = slices + grp * GRP_BYTES;
  char* myslice   = slices + grp * GRP_BYTES + wgN * SLICE_BYTES;

  float cst[2][2][4];            // fp32 cell state, register-resident
  #pragma unroll
  for (int a = 0; a < 2; ++a)
    #pragma unroll
    for (int b = 0; b < 2; ++b)
      #pragma unroll
      for (int r = 0; r < 4; ++r) cst[a][b][r] = 0.f;

  int rB[2], swzB[2];            // B-fragment LDS rows for this lane
  #pragma unroll
  for (int nt = 0; nt < 2; ++nt) {
    rB[nt] = (ch * 2 + nt) * 16 + q * 4 + gs;
    swzB[nt] = (rB[nt] & 7) << 4;
  }

  __syncthreads();

  #pragma unroll 1
  for (int t = 0; t < NSTEPS; ++t) {
    if (t > 0) {
      if (tid == 0) {
        while (__hip_atomic_load(cnt, __ATOMIC_RELAXED, __HIP_MEMORY_SCOPE_AGENT) < (u32)(32 * t))
          __builtin_amdgcn_s_sleep(1);
      }
      __syncthreads();
      __builtin_amdgcn_fence(__ATOMIC_ACQUIRE, "agent");   // invalidate stale L1/L2
    }

    // ---- stage h_{t-1} (read slot = (t&1)^1): issue global loads early ----
    const char* rdbase = grpslices + (size_t)((t & 1) ^ 1) * SLOT_BYTES;
    uint4 stg[16];
    #pragma unroll
    for (int it = 0; it < 16; ++it) {
      int s = it * 256 + tid;    // source 16B granule, coalesced
      stg[it] = *(const uint4*)(rdbase + (s >> 7) * SLICE_BYTES + ((s >> 1) & 63) * 32 + (s & 1) * 16);
    }

    f32x4 acc[2][2] = {};
    // ---- x-part (k 0..255) overlaps staging latency ----
    const u16* xbase = xb + (size_t)(grp * 64 + rh * 32 + cc) * 65536 + t * 256 + hi * 8;
    #pragma unroll
    for (int kc = 0; kc < 8; ++kc) {
      bf16x8 bfr[2];
      #pragma unroll
      for (int nt = 0; nt < 2; ++nt)
        bfr[nt] = *(const bf16x8*)(smem + rB[nt] * W_ROWB + ((kc * 64 + hi * 16) ^ swzB[nt]));
      #pragma unroll
      for (int mt = 0; mt < 2; ++mt) {
        bf16x8 afr = __builtin_bit_cast(bf16x8, *(const uint4*)(xbase + mt * 16 * 65536 + kc * 32));
        #pragma unroll
        for (int nt = 0; nt < 2; ++nt)
          acc[mt][nt] = __builtin_amdgcn_mfma_f32_16x16x32_bf16(afr, bfr[nt], acc[mt][nt], 0, 0, 0);
      }
    }

    // ---- write staged h into LDS (swizzled) ----
    #pragma unroll
    for (int it = 0; it < 16; ++it) {
      int s = it * 256 + tid;
      int bb = (s >> 1) & 63;
      int gd = (((s >> 7) * 2 + (s & 1)) ^ (bb & 7));
      *(uint4*)(smem + H_OFF + bb * 1024 + gd * 16) = stg[it];
    }
    __syncthreads();

    // ---- h-part (k 256..767) ----
    #pragma unroll
    for (int kc = 0; kc < 16; ++kc) {
      bf16x8 bfr[2];
      #pragma unroll
      for (int nt = 0; nt < 2; ++nt)
        bfr[nt] = *(const bf16x8*)(smem + rB[nt] * W_ROWB + (((kc + 8) * 64 + hi * 16) ^ swzB[nt]));
      #pragma unroll
      for (int mt = 0; mt < 2; ++mt) {
        int bloc = rh * 32 + mt * 16 + cc;
        bf16x8 afr = *(const bf16x8*)(smem + H_OFF + bloc * 1024 + ((kc * 64 + hi * 16) ^ ((bloc & 7) << 4)));
        #pragma unroll
        for (int nt = 0; nt < 2; ++nt)
          acc[mt][nt] = __builtin_amdgcn_mfma_f32_16x16x32_bf16(afr, bfr[nt], acc[mt][nt], 0, 0, 0);
      }
    }

    // ---- gates -> (i,f,g,o) via shfl, state update, h write ----
    char* wslice = myslice + (size_t)(t & 1) * SLOT_BYTES;
    #pragma unroll
    for (int mt = 0; mt < 2; ++mt)
      #pragma unroll
      for (int nt = 0; nt < 2; ++nt)
        #pragma unroll
        for (int r = 0; r < 4; ++r) {
          float v = acc[mt][nt][r] + biasv[nt];
          float vi = __shfl(v, (lane & 48) | q);
          float vf = __shfl(v, (lane & 48) | (q + 4));
          float vg = __shfl(v, (lane & 48) | (q + 8));
          float vo = __shfl(v, (lane & 48) | (q + 12));
          float ii = sigm(vi), ff = sigm(vf), gg = tanh_(vg), oo = sigm(vo);
          float cn = ff * cst[mt][nt][r] + ii * gg;
          cst[mt][nt][r] = cn;
          float hn = oo * tanh_(cn);
          if (gs == 0) {
            int b = rh * 32 + mt * 16 + hi * 4 + r;
            int col = (ch * 2 + nt) * 4 + q;
            *(u16*)(wslice + b * 32 + col * 2) = f2bf(hn);
          }
        }

    __builtin_amdgcn_fence(__ATOMIC_RELEASE, "agent");     // flush h-slice to L3
    __syncthreads();
    if (tid == 0)
      __hip_atomic_fetch_add(cnt, 1u, __ATOMIC_RELEASE, __HIP_MEMORY_SCOPE_AGENT);
  }

  // ---- head: one WG per group computes out = h_T @ W_out^T + b_out ----
  if (wgN == 0) {
    if (tid == 0) {
      while (__hip_atomic_load(cnt, __ATOMIC_RELAXED, __HIP_MEMORY_SCOPE_AGENT) < 8192u)
        __builtin_amdgcn_s_sleep(1);
    }
    __syncthreads();
    __builtin_amdgcn_fence(__ATOMIC_ACQUIRE, "agent");
    const char* rdbase = grpslices + SLOT_BYTES;           // slot 1 = h_255
    #pragma unroll
    for (int it = 0; it < 16; ++it) {
      int s = it * 256 + tid;
      uint4 v = *(const uint4*)(rdbase + (s >> 7) * SLICE_BYTES + ((s >> 1) & 63) * 32 + (s & 1) * 16);
      int bb = (s >> 1) & 63;
      int gd = (((s >> 7) * 2 + (s & 1)) ^ (bb & 7));
      *(uint4*)(smem + H_OFF + bb * 1024 + gd * 16) = v;
    }
    __syncthreads();
    int b = tid >> 2, qq = tid & 3;
    float s = 0.f;
    for (int j = qq * 128; j < qq * 128 + 128; ++j) {
      u16 hb = *(const u16*)(smem + H_OFF + b * 1024 + ((j * 2) ^ ((b & 7) << 4)));
      s += bf2f(hb) * W_out[j];
    }
    s += __shfl_xor(s, 1);
    s += __shfl_xor(s, 2);
    if (qq == 0) out[grp * 64 + b] = s + b_out[0];
  }
}

extern "C" void kernel_launch(void* const* d_in, const int* in_sizes, int n_in,
                              void* d_out, int out_size, void* d_ws, size_t ws_size,
                              hipStream_t stream) {
  (void)in_sizes; (void)n_in; (void)out_size; (void)ws_size;
  const float* x     = (const float*)d_in[0];
  const float* W_ih  = (const float*)d_in[1];
  const float* W_hh  = (const float*)d_in[2];
  const float* b_ih  = (const float*)d_in[3];
  const float* b_hh  = (const float*)d_in[4];
  const float* W_out = (const float*)d_in[5];
  const float* b_out = (const float*)d_in[6];
  char* ws = (char*)d_ws;

  // zero h-exchange slots + group counters (re-runs every graph replay)
  hipMemsetAsync(ws + SL_OFF, 0, 2u * SLOT_BYTES + 1024u, stream);
  cvt_x<<<32768, 256, 0, stream>>>(x, (u16*)ws);
  lstm_main<<<256, 256, 0, stream>>>((const u16*)ws, W_ih, W_hh, b_ih, b_hh,
                                     W_out, b_out, (float*)d_out, ws);
}

// Round 2
// 1277.470 us; speedup vs baseline: 5.7361x; 5.7361x over previous
//
#include <hip/hip_runtime.h>
#include <stdint.h>

typedef unsigned int u32;
typedef unsigned short u16;
typedef __attribute__((ext_vector_type(8))) __bf16 bf16x8;
typedef __attribute__((ext_vector_type(4))) float f32x4;
typedef __attribute__((ext_vector_type(4))) u32 u32x4;

#define NSTEPS 256
// ---- workspace layout ----
#define XB_BYTES   67108864u              // x as bf16: 512*256*256*2
#define SL_OFF     XB_BYTES               // h slots: [slot][group][wgN][64 rows][16 cols] bf16
#define GRP_BYTES   65536u                // 32 wg * 2KB
#define SLOT_BYTES  524288u               // 8 groups
#define CNT_OFF    (SL_OFF + 2u * SLOT_BYTES)
// ---- LDS layout ----
#define W_ROWB 1536                       // 768 bf16 per weight row (row = gate*16 + localcol)
#define H_OFF  98304                      // 64 rows * 1536
#define LDS_TOTAL 163840                  // + 64 rows * 1024 (h tile) = 160 KiB exactly

static __device__ __forceinline__ u16 f2bf(float f) {
  u32 u = __builtin_bit_cast(u32, f);
  return (u16)((u + 0x7fffu + ((u >> 16) & 1u)) >> 16);   // RNE
}
static __device__ __forceinline__ float bf2f(u16 h) {
  u32 u = ((u32)h) << 16;
  return __builtin_bit_cast(float, u);
}
static __device__ __forceinline__ float sigm(float x) {
  return __builtin_amdgcn_rcpf(1.f + __builtin_amdgcn_exp2f(-1.4426950408889634f * x));
}
static __device__ __forceinline__ float tanh_(float x) {
  return 1.f - 2.f * __builtin_amdgcn_rcpf(1.f + __builtin_amdgcn_exp2f(2.8853900817779268f * x));
}

// device-coherent (bypass L1/L2) primitives — no cache-wide fences needed
static __device__ __forceinline__ u32 poll_sc(const u32* p) {
  u32 v;
  asm volatile("global_load_dword %0, %1, off sc0 sc1\n\t"
               "s_waitcnt vmcnt(0)"
               : "=v"(v) : "v"(p) : "memory");
  return v;
}
static __device__ __forceinline__ void st16_sc(void* p, u32 v) {
  asm volatile("global_store_short %0, %1, off sc0 sc1" :: "v"(p), "v"(v) : "memory");
}
// issue 8 cached x loads (no wait)
static __device__ __forceinline__ void xissue(u32x4 x[8], const void* base) {
  asm volatile(
    "global_load_dwordx4 %0, %8, off offset:0\n\t"
    "global_load_dwordx4 %1, %8, off offset:64\n\t"
    "global_load_dwordx4 %2, %8, off offset:128\n\t"
    "global_load_dwordx4 %3, %8, off offset:192\n\t"
    "global_load_dwordx4 %4, %8, off offset:256\n\t"
    "global_load_dwordx4 %5, %8, off offset:320\n\t"
    "global_load_dwordx4 %6, %8, off offset:384\n\t"
    "global_load_dwordx4 %7, %8, off offset:448"
    : "=&v"(x[0]), "=&v"(x[1]), "=&v"(x[2]), "=&v"(x[3]),
      "=&v"(x[4]), "=&v"(x[5]), "=&v"(x[6]), "=&v"(x[7])
    : "v"(base) : "memory");
}
// issue 16 device-coherent staging loads (no wait); src = base + tid*16 + it*4096
static __device__ __forceinline__ void sissue(u32x4 s[16], const char* b) {
  asm volatile(
    "global_load_dwordx4 %0, %16, off sc0 sc1\n\t"
    "global_load_dwordx4 %1, %17, off sc0 sc1\n\t"
    "global_load_dwordx4 %2, %18, off sc0 sc1\n\t"
    "global_load_dwordx4 %3, %19, off sc0 sc1\n\t"
    "global_load_dwordx4 %4, %20, off sc0 sc1\n\t"
    "global_load_dwordx4 %5, %21, off sc0 sc1\n\t"
    "global_load_dwordx4 %6, %22, off sc0 sc1\n\t"
    "global_load_dwordx4 %7, %23, off sc0 sc1\n\t"
    "global_load_dwordx4 %8, %24, off sc0 sc1\n\t"
    "global_load_dwordx4 %9, %25, off sc0 sc1\n\t"
    "global_load_dwordx4 %10, %26, off sc0 sc1\n\t"
    "global_load_dwordx4 %11, %27, off sc0 sc1\n\t"
    "global_load_dwordx4 %12, %28, off sc0 sc1\n\t"
    "global_load_dwordx4 %13, %29, off sc0 sc1\n\t"
    "global_load_dwordx4 %14, %30, off sc0 sc1\n\t"
    "global_load_dwordx4 %15, %31, off sc0 sc1"
    : "=&v"(s[0]), "=&v"(s[1]), "=&v"(s[2]), "=&v"(s[3]),
      "=&v"(s[4]), "=&v"(s[5]), "=&v"(s[6]), "=&v"(s[7]),
      "=&v"(s[8]), "=&v"(s[9]), "=&v"(s[10]), "=&v"(s[11]),
      "=&v"(s[12]), "=&v"(s[13]), "=&v"(s[14]), "=&v"(s[15])
    : "v"(b), "v"(b + 4096), "v"(b + 8192), "v"(b + 12288),
      "v"(b + 16384), "v"(b + 20480), "v"(b + 24576), "v"(b + 28672),
      "v"(b + 32768), "v"(b + 36864), "v"(b + 40960), "v"(b + 45056),
      "v"(b + 49152), "v"(b + 53248), "v"(b + 57344), "v"(b + 61440)
    : "memory");
}
static __device__ __forceinline__ void wait16() {
  asm volatile("s_waitcnt vmcnt(16)" ::: "memory");
  __builtin_amdgcn_sched_barrier(0);
}
static __device__ __forceinline__ void wait0() {
  asm volatile("s_waitcnt vmcnt(0)" ::: "memory");
  __builtin_amdgcn_sched_barrier(0);
}

__global__ void cvt_x(const float* __restrict__ x, u16* __restrict__ xb) {
  int i = blockIdx.x * 256 + threadIdx.x;          // one float4 per thread
  float4 v = ((const float4*)x)[i];
  ushort4 o;
  o.x = f2bf(v.x); o.y = f2bf(v.y); o.z = f2bf(v.z); o.w = f2bf(v.w);
  ((ushort4*)xb)[i] = o;
}

// 256 WGs: group = wg&7 owns batch rows [grp*64,+64); wgN = wg>>3 owns hidden
// cols [wgN*16,+16) of all 4 gates. Wave wv: 16 batch rows; nt = gate index.
__global__ void __launch_bounds__(256) lstm_main(
    const u16* __restrict__ xb,
    const float* __restrict__ W_ih, const float* __restrict__ W_hh,
    const float* __restrict__ b_ih, const float* __restrict__ b_hh,
    const float* __restrict__ W_out, const float* __restrict__ b_out,
    float* __restrict__ out, char* __restrict__ ws)
{
  __shared__ char smem[LDS_TOTAL];
  const int tid = threadIdx.x;
  const int wg  = blockIdx.x;
  const int grp = wg & 7;
  const int wgN = wg >> 3;
  const int lane = tid & 63;
  const int wv   = tid >> 6;
  const int cc = lane & 15;
  const int hi = lane >> 4;

  // ---- one-time: weight slice -> LDS, bf16, XOR-swizzled (row = gate*16+lc) ----
  for (int i = tid; i < 64 * 192; i += 256) {
    int r = i / 192;
    int k = (i - r * 192) * 4;
    int n = (r >> 4) * 512 + wgN * 16 + (r & 15);
    float4 v = (k < 256) ? *(const float4*)(W_ih + n * 256 + k)
                         : *(const float4*)(W_hh + n * 512 + (k - 256));
    u32 lo  = (u32)f2bf(v.x) | ((u32)f2bf(v.y) << 16);
    u32 hi2 = (u32)f2bf(v.z) | ((u32)f2bf(v.w) << 16);
    int addr = r * W_ROWB + ((k * 2) ^ ((r & 7) << 4));
    *(uint2*)(smem + addr) = make_uint2(lo, hi2);
  }

  float bv[4];
  #pragma unroll
  for (int nt = 0; nt < 4; ++nt) {
    int n = nt * 512 + wgN * 16 + cc;
    bv[nt] = b_ih[n] + b_hh[n];
  }

  u32* cnt = (u32*)(ws + CNT_OFF + grp * 128);
  char* slices = ws + SL_OFF;
  const char* grpsl = slices + (size_t)grp * GRP_BYTES;

  const char* wrow[4];
  #pragma unroll
  for (int nt = 0; nt < 4; ++nt) wrow[nt] = smem + (nt * 16 + cc) * W_ROWB;
  const int wsw = (cc & 7) << 4;            // rows used by this lane are ≡ cc (mod 8)
  const int hw  = (hi * 16) ^ wsw;          // disjoint-bit XOR fold
  const char* arow = smem + H_OFF + (wv * 16 + cc) * 1024;

  const u16* xrow = xb + (size_t)(grp * 64 + wv * 16 + cc) * 65536 + hi * 8;

  // staging ds-write mapping (constant across t)
  const int srow  = (tid & 127) >> 1;
  const int shalf = tid & 1;
  const int swgb  = tid >> 7;
  char* sdst0 = smem + H_OFF + srow * 1024;
  const int sswz = (srow & 7) << 4;

  float cst[4] = {0.f, 0.f, 0.f, 0.f};      // fp32 cell state

  __syncthreads();

  #pragma unroll 1
  for (int t = 0; t < NSTEPS; ++t) {
    u32x4 xreg[8];
    xissue(xreg, xrow + (size_t)t * 256);

    if (t > 0) {
      u32 tgt = 32u * (u32)t;
      while (poll_sc(cnt) < tgt) __builtin_amdgcn_s_sleep(1);
    }

    // ---- stage h_{t-1}: issue device-coherent loads, overlap with x-part ----
    const char* rdslot = grpsl + (size_t)((t & 1) ^ 1) * SLOT_BYTES + tid * 16;
    u32x4 sv[16];
    sissue(sv, rdslot);
    wait16();                               // x loads (oldest 8) complete

    f32x4 acc[4] = {}, acc2[4] = {};
    #pragma unroll
    for (int kc = 0; kc < 8; ++kc) {
      bf16x8 a = __builtin_bit_cast(bf16x8, xreg[kc]);
      #pragma unroll
      for (int nt = 0; nt < 4; ++nt) {
        bf16x8 b = *(const bf16x8*)(wrow[nt] + ((kc * 64) ^ hw));
        if (kc & 1) acc2[nt] = __builtin_amdgcn_mfma_f32_16x16x32_bf16(a, b, acc2[nt], 0, 0, 0);
        else        acc[nt]  = __builtin_amdgcn_mfma_f32_16x16x32_bf16(a, b, acc[nt], 0, 0, 0);
      }
    }

    wait0();                                // staging loads complete
    #pragma unroll
    for (int it = 0; it < 16; ++it) {
      int wgn = it * 2 + swgb;
      *(u32x4*)(sdst0 + ((wgn * 32 + shalf * 16) ^ sswz)) = sv[it];
    }
    __syncthreads();

    // ---- h-part (k 256..767) ----
    #pragma unroll
    for (int kc = 0; kc < 16; ++kc) {
      bf16x8 a = *(const bf16x8*)(arow + ((kc * 64) ^ hw));
      #pragma unroll
      for (int nt = 0; nt < 4; ++nt) {
        bf16x8 b = *(const bf16x8*)(wrow[nt] + (((kc + 8) * 64) ^ hw));
        if (kc & 1) acc2[nt] = __builtin_amdgcn_mfma_f32_16x16x32_bf16(a, b, acc2[nt], 0, 0, 0);
        else        acc[nt]  = __builtin_amdgcn_mfma_f32_16x16x32_bf16(a, b, acc[nt], 0, 0, 0);
      }
    }

    // ---- gates (all lane-local: nt = gate), state update, h store ----
    char* wdst = slices + (size_t)(t & 1) * SLOT_BYTES + grp * GRP_BYTES + wgN * 2048;
    #pragma unroll
    for (int r = 0; r < 4; ++r) {
      float gi = acc[0][r] + acc2[0][r] + bv[0];
      float gf = acc[1][r] + acc2[1][r] + bv[1];
      float gg = acc[2][r] + acc2[2][r] + bv[2];
      float go = acc[3][r] + acc2[3][r] + bv[3];
      float ii = sigm(gi), ff = sigm(gf), g2 = tanh_(gg), oo = sigm(go);
      float cn = ff * cst[r] + ii * g2;
      cst[r] = cn;
      float hn = oo * tanh_(cn);
      int row = wv * 16 + hi * 4 + r;
      st16_sc(wdst + row * 32 + cc * 2, (u32)f2bf(hn));
    }
    asm volatile("s_waitcnt vmcnt(0)" ::: "memory");   // own stores at coherence point
    __syncthreads();
    if (tid == 0) atomicAdd(cnt, 1u);
  }

  // ---- head: one WG per group computes out = h_T @ W_out^T + b_out ----
  if (wgN == 0) {
    while (poll_sc(cnt) < 32u * NSTEPS) __builtin_amdgcn_s_sleep(1);
    const char* src = grpsl + SLOT_BYTES + tid * 16;   // slot 1 = h_255
    u32x4 sv[16];
    sissue(sv, src);
    wait0();
    #pragma unroll
    for (int it = 0; it < 16; ++it) {
      int wgn = it * 2 + swgb;
      *(u32x4*)(smem + H_OFF + srow * 1024 + wgn * 32 + shalf * 16) = sv[it];  // linear
    }
    __syncthreads();
    int b = tid >> 2, q = tid & 3;
    float s = 0.f;
    for (int j = q * 128; j < q * 128 + 128; ++j)
      s += bf2f(*(const u16*)(smem + H_OFF + b * 1024 + j * 2)) * W_out[j];
    s += __shfl_xor(s, 1);
    s += __shfl_xor(s, 2);
    if (q == 0) out[grp * 64 + b] = s + b_out[0];
  }
}

extern "C" void kernel_launch(void* const* d_in, const int* in_sizes, int n_in,
                              void* d_out, int out_size, void* d_ws, size_t ws_size,
                              hipStream_t stream) {
  (void)in_sizes; (void)n_in; (void)out_size; (void)ws_size;
  const float* x     = (const float*)d_in[0];
  const float* W_ih  = (const float*)d_in[1];
  const float* W_hh  = (const float*)d_in[2];
  const float* b_ih  = (const float*)d_in[3];
  const float* b_hh  = (const float*)d_in[4];
  const float* W_out = (const float*)d_in[5];
  const float* b_out = (const float*)d_in[6];
  char* ws = (char*)d_ws;

  // zero h-exchange slots + group counters (re-runs every graph replay)
  hipMemsetAsync(ws + SL_OFF, 0, 2u * SLOT_BYTES + 1024u, stream);
  cvt_x<<<32768, 256, 0, stream>>>(x, (u16*)ws);
  lstm_main<<<256, 256, 0, stream>>>((const u16*)ws, W_ih, W_hh, b_ih, b_hh,
                                     W_out, b_out, (float*)d_out, ws);
}